// Round 13
// baseline (268.593 us; speedup 1.0000x reference)
//
#include <hip/hip_runtime.h>
#include <hip/hip_bf16.h>

#define HID 128
#define BSH 6            // 64 nodes per bucket
#define MAXBUCK 2048     // >= ceil(n/64); n=100000 -> 1563
#define NSB 256          // edge chunks
#define SORTCAP 12800    // per-chunk LDS sort capacity (chunk = E/NSB = 12500)
#define CAP 2816         // per-bucket LDS edge capacity in agg (mean 2048)

__device__ __forceinline__ float b2f(unsigned short u) {
    union { unsigned i; float f; } v; v.i = ((unsigned)u) << 16; return v.f;
}
__device__ __forceinline__ unsigned short f2b(float f) {
    unsigned u = __float_as_uint(f);
    return (unsigned short)((u + 0x7fffu + ((u >> 16) & 1u)) >> 16);  // RNE
}

// ---------------- K1: per-chunk bucket histogram ----------------
__global__ __launch_bounds__(256) void histblk_kernel(const int* __restrict__ ei,
                                                      unsigned* __restrict__ hist,
                                                      int E, int n, int nbuck) {
    __shared__ unsigned h[MAXBUCK];
    for (int i = threadIdx.x; i < nbuck; i += 256) h[i] = 0u;
    __syncthreads();
    int blk = blockIdx.x;
    int chunk = (E + NSB - 1) / NSB;
    int beg = blk * chunk, end = min(E, beg + chunk);
    for (int i = beg + threadIdx.x; i < end; i += 256) {
        int dst = ei[(size_t)E + i];
        if ((unsigned)dst < (unsigned)n) atomicAdd(&h[dst >> BSH], 1u);
    }
    __syncthreads();
    for (int b = threadIdx.x; b < nbuck; b += 256)
        hist[(size_t)blk * nbuck + b] = h[b];
}

// ---------------- K2: per-bucket exclusive scan over the NSB chunks (1/thread) ----------------
__global__ __launch_bounds__(256) void scan2d_kernel(const unsigned* __restrict__ hist,
                                                     unsigned* __restrict__ base_rel,
                                                     unsigned* __restrict__ bcount,
                                                     int nbuck) {
    int b = blockIdx.x;
    int t = threadIdx.x;
    unsigned v = hist[(size_t)t * nbuck + b];
    int lane = t & 63, w = t >> 6;
    unsigned x = v;
    for (int d = 1; d < 64; d <<= 1) {
        unsigned y = __shfl_up(x, d, 64);
        if (lane >= d) x += y;
    }
    __shared__ unsigned wsum[4];
    if (lane == 63) wsum[w] = x;
    __syncthreads();
    unsigned add = 0;
    for (int ww = 0; ww < 4; ++ww) if (ww < w) add += wsum[ww];
    unsigned incl = x + add;
    base_rel[(size_t)t * nbuck + b] = incl - v;
    if (t == 255) bcount[b] = incl;
}

// ---------------- K3: scan of bucket counts (single block) ----------------
__global__ __launch_bounds__(1024) void bscan_kernel(const unsigned* __restrict__ bcount,
                                                     unsigned* __restrict__ boff,
                                                     int nbuck) {
    __shared__ unsigned sums[1024];
    int t = threadIdx.x;
    int chunk = (nbuck + 1023) >> 10;
    int beg = min(t * chunk, nbuck), end = min(beg + chunk, nbuck);
    unsigned local = 0;
    for (int i = beg; i < end; ++i) local += bcount[i];
    sums[t] = local;
    __syncthreads();
    for (int d = 1; d < 1024; d <<= 1) {
        unsigned v = (t >= d) ? sums[t - d] : 0u;
        __syncthreads();
        sums[t] += v;
        __syncthreads();
    }
    unsigned run = (t > 0) ? sums[t - 1] : 0u;
    for (int i = beg; i < end; ++i) { boff[i] = run; run += bcount[i]; }
    if (t == 1023) boff[nbuck] = sums[1023];
}

// ---------------- K4 (fused): LDS-counting-sort binscatter (blocks 0..NSB-1) + 64-row gemm ----------------
// binned[pos] = (dst&63)<<20 | src, grouped by bucket, written COALESCED.
// gemm: hp = (x+h_cur)@W[:,0:128] bf16 flat [n][128]
__global__ __launch_bounds__(256) void binsort_kernel(const int* __restrict__ ei,
                                                      const unsigned* __restrict__ boff,
                                                      const unsigned* __restrict__ base_rel,
                                                      unsigned* __restrict__ binned,
                                                      const float* __restrict__ x,
                                                      const float* __restrict__ hc,
                                                      const float* __restrict__ W,
                                                      unsigned short* __restrict__ hp,
                                                      int E, int n, int nbuck) {
    __shared__ union {
        struct {
            unsigned sorted[SORTCAP];       // 51.2 KB
            unsigned lexcl[MAXBUCK + 1];    // 8 KB
            unsigned cursor[MAXBUCK];       // 8 KB
            unsigned gbase[MAXBUCK];        // 8 KB
        } bs;
        float A[64 * 132];                  // 33.8 KB
    } sm;

    int tid = threadIdx.x;
    if (blockIdx.x < NSB) {
        int blk = blockIdx.x;
        int chunk = (E + NSB - 1) / NSB;
        int beg = blk * chunk, end = min(E, beg + chunk);

        if (end - beg <= SORTCAP) {
            // ---- pass A: local bucket histogram (into cursor) ----
            for (int b = tid; b < nbuck; b += 256) sm.bs.cursor[b] = 0u;
            __syncthreads();
            for (int i = beg + tid; i < end; i += 256) {
                int dst = ei[(size_t)E + i];
                if ((unsigned)dst < (unsigned)n) atomicAdd(&sm.bs.cursor[dst >> BSH], 1u);
            }
            __syncthreads();
            // ---- block scan over buckets: thread t handles K consecutive buckets ----
            int K = (nbuck + 255) / 256;
            int b0 = tid * K, b1 = min(b0 + K, nbuck);
            unsigned partial = 0;
            for (int b = b0; b < b1; ++b) partial += sm.bs.cursor[b];
            int lane = tid & 63, w = tid >> 6;
            unsigned xs = partial;
            for (int d = 1; d < 64; d <<= 1) {
                unsigned y = __shfl_up(xs, d, 64);
                if (lane >= d) xs += y;
            }
            __shared__ unsigned wsum[4];
            if (lane == 63) wsum[w] = xs;
            __syncthreads();
            unsigned add = 0;
            for (int ww = 0; ww < 4; ++ww) if (ww < w) add += wsum[ww];
            unsigned run = xs + add - partial;   // exclusive prefix for b0
            for (int b = b0; b < b1; ++b) {
                unsigned cnt_b = sm.bs.cursor[b];
                sm.bs.lexcl[b] = run;
                sm.bs.gbase[b] = boff[b] + base_rel[(size_t)blk * nbuck + b];
                sm.bs.cursor[b] = run;
                run += cnt_b;
            }
            if (tid == 255) sm.bs.lexcl[nbuck] = xs + add;   // total valid
            __syncthreads();
            // ---- pass B: place into LDS sorted buffer ----
            for (int i = beg + tid; i < end; i += 256) {
                int s = ei[i];
                int dst = ei[(size_t)E + i];
                if ((unsigned)dst >= (unsigned)n) continue;
                unsigned ss = (unsigned)min(max(s, 0), n - 1);
                unsigned slot = atomicAdd(&sm.bs.cursor[dst >> BSH], 1u);
                sm.bs.sorted[slot] = ss | ((unsigned)(dst & ((1 << BSH) - 1)) << 20);
            }
            __syncthreads();
            // ---- write-out: consecutive lanes -> consecutive addresses (coalesced) ----
            unsigned cnt = sm.bs.lexcl[nbuck];
            for (unsigned i = tid; i < cnt; i += 256) {
                int lo = 0, hi = nbuck - 1;
                while (lo < hi) {   // largest b with lexcl[b] <= i
                    int mid = (lo + hi + 1) >> 1;
                    if (sm.bs.lexcl[mid] <= i) lo = mid; else hi = mid - 1;
                }
                unsigned gpos = sm.bs.gbase[lo] + (i - sm.bs.lexcl[lo]);
                binned[gpos] = sm.bs.sorted[i];
            }
        } else {
            // fallback: direct scatter (correct, slower) — never for this data
            for (int b = tid; b < nbuck; b += 256)
                sm.bs.cursor[b] = boff[b] + base_rel[(size_t)blk * nbuck + b];
            __syncthreads();
            for (int i = beg + tid; i < end; i += 256) {
                int s = ei[i];
                int dst = ei[(size_t)E + i];
                if ((unsigned)dst >= (unsigned)n) continue;
                unsigned ss = (unsigned)min(max(s, 0), n - 1);
                unsigned slot = atomicAdd(&sm.bs.cursor[dst >> BSH], 1u);
                binned[slot] = ss | ((unsigned)(dst & ((1 << BSH) - 1)) << 20);
            }
        }
    } else {
        // ---- gemm: 64-row tile ----
        int r0 = (blockIdx.x - NSB) * 64;

        for (int i = tid; i < 2048; i += 256) {
            int row = i >> 5;
            int c4 = (i & 31) * 4;
            int grow = r0 + row;
            float4 v;
            if (grow < n) {
                float4 a = *(const float4*)(x + (size_t)grow * HID + c4);
                float4 bb = *(const float4*)(hc + (size_t)grow * HID + c4);
                v = make_float4(a.x + bb.x, a.y + bb.y, a.z + bb.z, a.w + bb.w);
            } else {
                v = make_float4(0.f, 0.f, 0.f, 0.f);
            }
            *(float4*)(&sm.A[row * 132 + c4]) = v;
        }
        __syncthreads();

        int cg = tid & 31;
        int c4 = cg * 4;
        int rg = tid >> 5;
        float acc[8][4];
#pragma unroll
        for (int r = 0; r < 8; ++r) {
            acc[r][0] = 0.f; acc[r][1] = 0.f; acc[r][2] = 0.f; acc[r][3] = 0.f;
        }

#pragma unroll 4
        for (int k = 0; k < 128; ++k) {
            float4 w = *(const float4*)(W + (size_t)k * 512 + c4);
#pragma unroll
            for (int r = 0; r < 8; ++r) {
                float a = sm.A[(rg * 8 + r) * 132 + k];
                acc[r][0] += a * w.x;
                acc[r][1] += a * w.y;
                acc[r][2] += a * w.z;
                acc[r][3] += a * w.w;
            }
        }

#pragma unroll
        for (int r = 0; r < 8; ++r) {
            int grow = r0 + rg * 8 + r;
            if (grow < n) {
                unsigned long long pack =
                    (unsigned long long)f2b(acc[r][0]) |
                    ((unsigned long long)f2b(acc[r][1]) << 16) |
                    ((unsigned long long)f2b(acc[r][2]) << 32) |
                    ((unsigned long long)f2b(acc[r][3]) << 48);
                *(unsigned long long*)(hp + (size_t)grow * HID + c4) = pack;
            }
        }
    }
}

// ---------------- K5: per-bucket degree -> off[node], dinv[node] ----------------
__global__ __launch_bounds__(256) void csrlite_kernel(const unsigned* __restrict__ binned,
                                                      const unsigned* __restrict__ boff,
                                                      unsigned* __restrict__ off,
                                                      float* __restrict__ dinv, int n) {
    __shared__ unsigned hist[64];
    int b = blockIdx.x;
    int t = threadIdx.x;
    if (t < 64) hist[t] = 0u;
    __syncthreads();
    unsigned s0 = boff[b], s1 = boff[b + 1];
    for (unsigned j = s0 + t; j < s1; j += 256) atomicAdd(&hist[binned[j] >> 20], 1u);
    __syncthreads();
    if (t < 64) {
        unsigned cnt = hist[t];
        unsigned x = cnt;
        for (int d = 1; d < 64; d <<= 1) {
            unsigned v = __shfl_up(x, d, 64);
            if (t >= d) x += v;
        }
        unsigned excl = x - cnt;
        int node = (b << BSH) + t;
        if (node < n) {
            off[node] = s0 + excl;
            dinv[node] = rsqrtf((float)(cnt + 1u));  // +1 self-loop
        }
    }
}

// ---------------- K6: merged placement + aggregate (one bucket per block) ----------------
__global__ __launch_bounds__(256) void agg_merged_kernel(const unsigned* __restrict__ binned,
                                                         const unsigned* __restrict__ boff,
                                                         const unsigned* __restrict__ off,
                                                         const float* __restrict__ dinv,
                                                         const unsigned short* __restrict__ hp,
                                                         const float* __restrict__ bias,
                                                         float* __restrict__ out, int n) {
    __shared__ unsigned srcs_lds[CAP];
    __shared__ unsigned nodeoff[65];
    __shared__ unsigned cursor[64];
    __shared__ float sdinv[64];
    int b = blockIdx.x;
    int tid = threadIdx.x;
    unsigned s0 = boff[b], s1 = boff[b + 1];
    unsigned cnt = s1 - s0;
    int node0 = b << BSH;

    if (tid < 64) {
        int node = node0 + tid;
        unsigned o = (node < n) ? off[node] : s1;
        nodeoff[tid] = o - s0;
        cursor[tid] = o - s0;
        sdinv[tid] = (node < n) ? dinv[node] : 0.f;
    }
    if (tid == 64) nodeoff[64] = cnt;
    __syncthreads();

    if (cnt <= CAP) {
        for (unsigned j = s0 + tid; j < s1; j += 256) {
            unsigned p = binned[j];
            unsigned slot = atomicAdd(&cursor[p >> 20], 1u);
            srcs_lds[slot] = p & 0xFFFFFu;
        }
        __syncthreads();

        int w = tid >> 6, lane = tid & 63;
        int c = lane * 2;
        for (int nl = w * 16; nl < w * 16 + 16; ++nl) {
            int node = node0 + nl;
            if (node >= n) break;
            unsigned beg = nodeoff[nl], end2 = nodeoff[nl + 1];
            float ax = 0.f, ay = 0.f;
            unsigned i = beg;
            for (; i + 8 <= end2; i += 8) {
                unsigned s[8]; float wd[8]; ushort2 v[8];
#pragma unroll
                for (int j = 0; j < 8; ++j) s[j] = srcs_lds[i + j];
#pragma unroll
                for (int j = 0; j < 8; ++j) wd[j] = dinv[s[j]];
#pragma unroll
                for (int j = 0; j < 8; ++j) v[j] = *(const ushort2*)(hp + ((size_t)s[j] << 7) + c);
#pragma unroll
                for (int j = 0; j < 8; ++j) { ax += wd[j] * b2f(v[j].x); ay += wd[j] * b2f(v[j].y); }
            }
            if (i < end2) {
                unsigned last = end2 - 1;
                unsigned s[8]; float wd[8]; ushort2 v[8];
#pragma unroll
                for (int j = 0; j < 8; ++j) {
                    unsigned jj = i + j;
                    s[j] = srcs_lds[jj < end2 ? jj : last];
                    wd[j] = (jj < end2) ? 1.f : 0.f;
                }
#pragma unroll
                for (int j = 0; j < 8; ++j) wd[j] *= dinv[s[j]];
#pragma unroll
                for (int j = 0; j < 8; ++j) v[j] = *(const ushort2*)(hp + ((size_t)s[j] << 7) + c);
#pragma unroll
                for (int j = 0; j < 8; ++j) { ax += wd[j] * b2f(v[j].x); ay += wd[j] * b2f(v[j].y); }
            }
            float dd = sdinv[nl];
            ushort2 hd = *(const ushort2*)(hp + ((size_t)node << 7) + c);
            ax += dd * b2f(hd.x);
            ay += dd * b2f(hd.y);
            float2 bb = *(const float2*)(bias + c);
            float2 res = make_float2(dd * ax + bb.x, dd * ay + bb.y);
            *(float2*)(out + ((size_t)node << 7) + c) = res;
        }
    } else {
        // correctness-only fallback (never triggers for this data)
        for (int idx = tid; idx < 64 * HID; idx += 256) {
            int ndl = idx >> 7, col = idx & (HID - 1);
            int node = node0 + ndl;
            if (node < n) {
                float dd = sdinv[ndl];
                out[((size_t)node << 7) + col] = dd * dd * b2f(hp[((size_t)node << 7) + col]) + bias[col];
            }
        }
        __syncthreads();
        if (tid < 64) {
            int c = tid * 2;
            for (unsigned j = s0; j < s1; ++j) {
                unsigned p = binned[j];
                unsigned dl = p >> 20, s = p & 0xFFFFFu;
                float wsc = dinv[s] * sdinv[dl];
                ushort2 v = *(const ushort2*)(hp + ((size_t)s << 7) + c);
                float2* o = (float2*)(out + ((size_t)(node0 + dl) << 7) + c);
                float2 cur = *o;
                cur.x += wsc * b2f(v.x);
                cur.y += wsc * b2f(v.y);
                *o = cur;
            }
        }
    }
}

extern "C" void kernel_launch(void* const* d_in, const int* in_sizes, int n_in,
                              void* d_out, int out_size, void* d_ws, size_t ws_size,
                              hipStream_t stream) {
    const float* x = (const float*)d_in[0];
    const int* ei = (const int*)d_in[1];       // int32 per harness contract
    const float* hc = (const float*)d_in[2];
    // d_in[3] = c_cur unused
    const float* W = (const float*)d_in[4];
    const float* b = (const float*)d_in[5];
    float* out = (float*)d_out;

    int n = in_sizes[0] / HID;      // 100000
    int E = in_sizes[1] / 2;        // 3200000
    int nbuck = (n + 63) >> BSH;    // 1563 (<= MAXBUCK)

    // workspace layout (16B-aligned), total ~39.2 MB
    char* ws = (char*)d_ws;
    unsigned* bcount = (unsigned*)(ws);                    // 8KB region
    unsigned* boff   = (unsigned*)(ws + 8192);             // 8KB region (nbuck+1)
    unsigned* off    = (unsigned*)(ws + 24576);            // n*4 = 400000
    float*    dinv   = (float*)   (ws + 424576);           // n*4
    unsigned* binned = (unsigned*)(ws + 824576);           // E*4 = 12.8MB
    unsigned short* hp = (unsigned short*)(ws + 13624576); // [n][128] bf16 = 25.6MB

    // d_out doubles as scratch for hist/base_rel (3.2MB << 51.2MB);
    // agg_merged fully overwrites d_out afterwards.
    unsigned* hist     = (unsigned*)d_out;                 // [NSB][nbuck]
    unsigned* base_rel = hist + (size_t)NSB * nbuck;       // [NSB][nbuck]

    histblk_kernel<<<NSB, 256, 0, stream>>>(ei, hist, E, n, nbuck);
    scan2d_kernel<<<nbuck, 256, 0, stream>>>(hist, base_rel, bcount, nbuck);
    bscan_kernel<<<1, 1024, 0, stream>>>(bcount, boff, nbuck);

    int gemm_blocks = (n + 63) / 64;   // 1563
    binsort_kernel<<<NSB + gemm_blocks, 256, 0, stream>>>(ei, boff, base_rel, binned,
                                                          x, hc, W, hp, E, n, nbuck);
    csrlite_kernel<<<nbuck, 256, 0, stream>>>(binned, boff, off, dinv, n);
    agg_merged_kernel<<<nbuck, 256, 0, stream>>>(binned, boff, off, dinv, hp, b, out, n);
}

// Round 14
// 247.286 us; speedup vs baseline: 1.0862x; 1.0862x over previous
//
#include <hip/hip_runtime.h>
#include <hip/hip_bf16.h>

#define HID 128
#define NGR_SH 7          // 128 nodes per group
#define MAXGRP 1024       // >= ceil(n/128); n=100000 -> 782
#define NSB 256           // edge chunks
#define CAPG 4608         // per-group LDS edge capacity (mean 4092, sigma~64)

__device__ __forceinline__ float b2f(unsigned short u) {
    union { unsigned i; float f; } v; v.i = ((unsigned)u) << 16; return v.f;
}
__device__ __forceinline__ unsigned short f2b(float f) {
    unsigned u = __float_as_uint(f);
    return (unsigned short)((u + 0x7fffu + ((u >> 16) & 1u)) >> 16);  // RNE
}

// ---------------- K1 (fused): per-chunk group histogram (blocks 0..NSB-1) + 64-row gemm ----------------
__global__ __launch_bounds__(256) void histgemm_kernel(const int* __restrict__ ei,
                                                       unsigned* __restrict__ hist,
                                                       const float* __restrict__ x,
                                                       const float* __restrict__ hc,
                                                       const float* __restrict__ W,
                                                       unsigned short* __restrict__ hp,
                                                       int E, int n, int ngroups) {
    __shared__ union {
        unsigned h[MAXGRP];     // 4 KB
        float A[64 * 132];      // 33.8 KB
    } sm;
    int tid = threadIdx.x;

    if (blockIdx.x < NSB) {
        // ---- group histogram ----
        for (int g = tid; g < ngroups; g += 256) sm.h[g] = 0u;
        __syncthreads();
        int chunk = (E + NSB - 1) / NSB;
        int beg = blockIdx.x * chunk, end = min(E, beg + chunk);
        for (int i = beg + tid; i < end; i += 256) {
            int dst = ei[(size_t)E + i];
            if ((unsigned)dst < (unsigned)n) atomicAdd(&sm.h[dst >> NGR_SH], 1u);
        }
        __syncthreads();
        for (int g = tid; g < ngroups; g += 256)
            hist[(size_t)blockIdx.x * ngroups + g] = sm.h[g];
    } else {
        // ---- gemm: hp = (x+h_cur)@W[:,0:128] bf16 flat [n][128] ----
        int r0 = (blockIdx.x - NSB) * 64;
        for (int i = tid; i < 2048; i += 256) {
            int row = i >> 5;
            int c4 = (i & 31) * 4;
            int grow = r0 + row;
            float4 v;
            if (grow < n) {
                float4 a = *(const float4*)(x + (size_t)grow * HID + c4);
                float4 bb = *(const float4*)(hc + (size_t)grow * HID + c4);
                v = make_float4(a.x + bb.x, a.y + bb.y, a.z + bb.z, a.w + bb.w);
            } else {
                v = make_float4(0.f, 0.f, 0.f, 0.f);
            }
            *(float4*)(&sm.A[row * 132 + c4]) = v;
        }
        __syncthreads();

        int cg = tid & 31;
        int c4 = cg * 4;
        int rg = tid >> 5;
        float acc[8][4];
#pragma unroll
        for (int r = 0; r < 8; ++r) {
            acc[r][0] = 0.f; acc[r][1] = 0.f; acc[r][2] = 0.f; acc[r][3] = 0.f;
        }
#pragma unroll 4
        for (int k = 0; k < 128; ++k) {
            float4 w = *(const float4*)(W + (size_t)k * 512 + c4);
#pragma unroll
            for (int r = 0; r < 8; ++r) {
                float a = sm.A[(rg * 8 + r) * 132 + k];
                acc[r][0] += a * w.x;
                acc[r][1] += a * w.y;
                acc[r][2] += a * w.z;
                acc[r][3] += a * w.w;
            }
        }
#pragma unroll
        for (int r = 0; r < 8; ++r) {
            int grow = r0 + rg * 8 + r;
            if (grow < n) {
                unsigned long long pack =
                    (unsigned long long)f2b(acc[r][0]) |
                    ((unsigned long long)f2b(acc[r][1]) << 16) |
                    ((unsigned long long)f2b(acc[r][2]) << 32) |
                    ((unsigned long long)f2b(acc[r][3]) << 48);
                *(unsigned long long*)(hp + (size_t)grow * HID + c4) = pack;
            }
        }
    }
}

// ---------------- K2: per-group exclusive scan over the NSB chunks (1 chunk/thread) ----------------
__global__ __launch_bounds__(256) void scan2d_kernel(const unsigned* __restrict__ hist,
                                                     unsigned* __restrict__ base_rel,
                                                     unsigned* __restrict__ gcount,
                                                     int ngroups) {
    int g = blockIdx.x;
    int t = threadIdx.x;
    unsigned v = hist[(size_t)t * ngroups + g];
    int lane = t & 63, w = t >> 6;
    unsigned x = v;
    for (int d = 1; d < 64; d <<= 1) {
        unsigned y = __shfl_up(x, d, 64);
        if (lane >= d) x += y;
    }
    __shared__ unsigned wsum[4];
    if (lane == 63) wsum[w] = x;
    __syncthreads();
    unsigned add = 0;
    for (int ww = 0; ww < 4; ++ww) if (ww < w) add += wsum[ww];
    unsigned incl = x + add;
    base_rel[(size_t)t * ngroups + g] = incl - v;
    if (t == 255) gcount[g] = incl;
}

// ---------------- K3: scan of group counts (single block) ----------------
__global__ __launch_bounds__(1024) void gscan_kernel(const unsigned* __restrict__ gcount,
                                                     unsigned* __restrict__ gboff,
                                                     int ngroups) {
    __shared__ unsigned sums[1024];
    int t = threadIdx.x;
    int chunk = (ngroups + 1023) >> 10;
    int beg = min(t * chunk, ngroups), end = min(beg + chunk, ngroups);
    unsigned local = 0;
    for (int i = beg; i < end; ++i) local += gcount[i];
    sums[t] = local;
    __syncthreads();
    for (int d = 1; d < 1024; d <<= 1) {
        unsigned v = (t >= d) ? sums[t - d] : 0u;
        __syncthreads();
        sums[t] += v;
        __syncthreads();
    }
    unsigned run = (t > 0) ? sums[t - 1] : 0u;
    for (int i = beg; i < end; ++i) { gboff[i] = run; run += gcount[i]; }
    if (t == 1023) gboff[ngroups] = sums[1023];
}

// ---------------- K4: single-pass group scatter (high occupancy, 64B runs) ----------------
// grouped[pos] = src | (dst&127)<<17
__global__ __launch_bounds__(256) void gscatter_kernel(const int* __restrict__ ei,
                                                       const unsigned* __restrict__ gboff,
                                                       const unsigned* __restrict__ base_rel,
                                                       unsigned* __restrict__ grouped,
                                                       int E, int n, int ngroups) {
    __shared__ unsigned cursor[MAXGRP];   // 4 KB
    int blk = blockIdx.x;
    int tid = threadIdx.x;
    for (int g = tid; g < ngroups; g += 256)
        cursor[g] = gboff[g] + base_rel[(size_t)blk * ngroups + g];
    __syncthreads();
    int chunk = (E + NSB - 1) / NSB;
    int beg = blk * chunk, end = min(E, beg + chunk);
    for (int i = beg + tid; i < end; i += 256) {
        int s = ei[i];
        int dst = ei[(size_t)E + i];
        if ((unsigned)dst >= (unsigned)n) continue;
        unsigned ss = (unsigned)min(max(s, 0), n - 1);
        unsigned slot = atomicAdd(&cursor[dst >> NGR_SH], 1u);
        grouped[slot] = ss | ((unsigned)(dst & ((1 << NGR_SH) - 1)) << 17);
    }
}

// ---------------- K5: per-group degree -> dinv ----------------
__global__ __launch_bounds__(256) void dinvg_kernel(const unsigned* __restrict__ grouped,
                                                    const unsigned* __restrict__ gboff,
                                                    float* __restrict__ dinv, int n) {
    __shared__ unsigned lcnt[128];
    int g = blockIdx.x;
    int t = threadIdx.x;
    if (t < 128) lcnt[t] = 0u;
    __syncthreads();
    unsigned s0 = gboff[g], s1 = gboff[g + 1];
    for (unsigned j = s0 + t; j < s1; j += 256) atomicAdd(&lcnt[grouped[j] >> 17], 1u);
    __syncthreads();
    if (t < 128) {
        int node = (g << NGR_SH) + t;
        if (node < n) dinv[node] = rsqrtf((float)(lcnt[t] + 1u));  // +1 self-loop
    }
}

// ---------------- K6: per-group LDS sort + aggregate ----------------
__global__ __launch_bounds__(256) void aggsort_kernel(const unsigned* __restrict__ grouped,
                                                      const unsigned* __restrict__ gboff,
                                                      const float* __restrict__ dinv,
                                                      const unsigned short* __restrict__ hp,
                                                      const float* __restrict__ bias,
                                                      float* __restrict__ out, int n) {
    __shared__ unsigned srcs_lds[CAPG];   // 18.4 KB
    __shared__ unsigned nodeoff[129];
    __shared__ unsigned cursor[128];
    __shared__ float sdinv[128];
    __shared__ unsigned wtot[2];
    int g = blockIdx.x;
    int tid = threadIdx.x;
    unsigned s0 = gboff[g], s1 = gboff[g + 1];
    unsigned cnt = s1 - s0;
    int node0 = g << NGR_SH;

    if (tid < 128) {
        int node = node0 + tid;
        sdinv[tid] = (node < n) ? dinv[node] : 0.f;
        cursor[tid] = 0u;
    }
    __syncthreads();

    if (cnt <= CAPG) {
        // count local degrees
        for (unsigned j = s0 + tid; j < s1; j += 256) atomicAdd(&cursor[grouped[j] >> 17], 1u);
        __syncthreads();
        // exclusive scan of 128 counts (two 64-lane waves)
        if (tid < 128) {
            unsigned v = cursor[tid];
            int lane = tid & 63, w = tid >> 6;
            unsigned x = v;
            for (int d = 1; d < 64; d <<= 1) {
                unsigned y = __shfl_up(x, d, 64);
                if (lane >= d) x += y;
            }
            if (lane == 63) wtot[w] = x;
            __syncthreads();
            unsigned excl = x - v + ((w == 1) ? wtot[0] : 0u);
            nodeoff[tid] = excl;
            cursor[tid] = excl;
            if (tid == 127) nodeoff[128] = cnt;
        } else {
            __syncthreads();
        }
        __syncthreads();
        // place into per-node lists
        for (unsigned j = s0 + tid; j < s1; j += 256) {
            unsigned p = grouped[j];
            unsigned slot = atomicAdd(&cursor[p >> 17], 1u);
            srcs_lds[slot] = p & 0x1FFFFu;
        }
        __syncthreads();

        // gather: wave w handles nodes [w*32, w*32+32), 2 cols per lane, 8-deep MLP
        int w = tid >> 6, lane = tid & 63;
        int c = lane * 2;
        for (int nl = w * 32; nl < w * 32 + 32; ++nl) {
            int node = node0 + nl;
            if (node >= n) break;
            unsigned beg = nodeoff[nl], end2 = nodeoff[nl + 1];
            float ax = 0.f, ay = 0.f;
            unsigned i = beg;
            for (; i + 8 <= end2; i += 8) {
                unsigned s[8]; float wd[8]; ushort2 v[8];
#pragma unroll
                for (int j = 0; j < 8; ++j) s[j] = srcs_lds[i + j];
#pragma unroll
                for (int j = 0; j < 8; ++j) wd[j] = dinv[s[j]];
#pragma unroll
                for (int j = 0; j < 8; ++j) v[j] = *(const ushort2*)(hp + ((size_t)s[j] << 7) + c);
#pragma unroll
                for (int j = 0; j < 8; ++j) { ax += wd[j] * b2f(v[j].x); ay += wd[j] * b2f(v[j].y); }
            }
            if (i < end2) {
                unsigned last = end2 - 1;
                unsigned s[8]; float wd[8]; ushort2 v[8];
#pragma unroll
                for (int j = 0; j < 8; ++j) {
                    unsigned jj = i + j;
                    s[j] = srcs_lds[jj < end2 ? jj : last];
                    wd[j] = (jj < end2) ? 1.f : 0.f;
                }
#pragma unroll
                for (int j = 0; j < 8; ++j) wd[j] *= dinv[s[j]];
#pragma unroll
                for (int j = 0; j < 8; ++j) v[j] = *(const ushort2*)(hp + ((size_t)s[j] << 7) + c);
#pragma unroll
                for (int j = 0; j < 8; ++j) { ax += wd[j] * b2f(v[j].x); ay += wd[j] * b2f(v[j].y); }
            }
            float dd = sdinv[nl];
            ushort2 hd = *(const ushort2*)(hp + ((size_t)node << 7) + c);
            ax += dd * b2f(hd.x);
            ay += dd * b2f(hd.y);
            float2 bb = *(const float2*)(bias + c);
            float2 res = make_float2(dd * ax + bb.x, dd * ay + bb.y);
            *(float2*)(out + ((size_t)node << 7) + c) = res;
        }
    } else {
        // correctness-only fallback (never triggers for this data)
        for (int idx = tid; idx < 128 * HID; idx += 256) {
            int ndl = idx >> 7, col = idx & (HID - 1);
            int node = node0 + ndl;
            if (node < n) {
                float dd = sdinv[ndl];
                out[((size_t)node << 7) + col] = dd * dd * b2f(hp[((size_t)node << 7) + col]) + bias[col];
            }
        }
        __syncthreads();
        if (tid < 64) {   // wave 0 serial: lockstep, disjoint cols -> no race
            int c = tid * 2;
            for (unsigned j = s0; j < s1; ++j) {
                unsigned p = grouped[j];
                unsigned dl = p >> 17, s = p & 0x1FFFFu;
                float wsc = dinv[s] * sdinv[dl];
                ushort2 v = *(const ushort2*)(hp + ((size_t)s << 7) + c);
                float2* o = (float2*)(out + ((size_t)(node0 + dl) << 7) + c);
                float2 cur = *o;
                cur.x += wsc * b2f(v.x);
                cur.y += wsc * b2f(v.y);
                *o = cur;
            }
        }
    }
}

extern "C" void kernel_launch(void* const* d_in, const int* in_sizes, int n_in,
                              void* d_out, int out_size, void* d_ws, size_t ws_size,
                              hipStream_t stream) {
    const float* x = (const float*)d_in[0];
    const int* ei = (const int*)d_in[1];       // int32 per harness contract
    const float* hc = (const float*)d_in[2];
    // d_in[3] = c_cur unused
    const float* W = (const float*)d_in[4];
    const float* b = (const float*)d_in[5];
    float* out = (float*)d_out;

    int n = in_sizes[0] / HID;          // 100000
    int E = in_sizes[1] / 2;            // 3200000
    int ngroups = (n + 127) >> NGR_SH;  // 782 (<= MAXGRP)

    // workspace layout (16B-aligned), total ~39.2 MB
    char* ws = (char*)d_ws;
    unsigned* gcount = (unsigned*)(ws);                    // 8KB region
    unsigned* gboff  = (unsigned*)(ws + 8192);             // 8KB region (ngroups+1)
    float*    dinv   = (float*)   (ws + 16384);            // n*4 = 400000
    unsigned* grouped= (unsigned*)(ws + 416384);           // E*4 = 12.8MB
    unsigned short* hp = (unsigned short*)(ws + 13216384); // [n][128] bf16 = 25.6MB

    // d_out doubles as scratch for hist/base_rel (1.6MB << 51.2MB);
    // aggsort fully overwrites d_out afterwards.
    unsigned* hist     = (unsigned*)d_out;                 // [NSB][ngroups]
    unsigned* base_rel = hist + (size_t)NSB * ngroups;     // [NSB][ngroups]

    int gemm_blocks = (n + 63) / 64;   // 1563
    histgemm_kernel<<<NSB + gemm_blocks, 256, 0, stream>>>(ei, hist, x, hc, W, hp, E, n, ngroups);
    scan2d_kernel<<<ngroups, 256, 0, stream>>>(hist, base_rel, gcount, ngroups);
    gscan_kernel<<<1, 1024, 0, stream>>>(gcount, gboff, ngroups);
    gscatter_kernel<<<NSB, 256, 0, stream>>>(ei, gboff, base_rel, grouped, E, n, ngroups);
    dinvg_kernel<<<ngroups, 256, 0, stream>>>(grouped, gboff, dinv, n);
    aggsort_kernel<<<ngroups, 256, 0, stream>>>(grouped, gboff, dinv, hp, b, out, n);
}